// Round 8
// baseline (503.370 us; speedup 1.0000x reference)
//
#include <hip/hip_runtime.h>
#include <hip/hip_cooperative_groups.h>
#include <math.h>

namespace cg = cooperative_groups;

// PointLaplacianLoss — grid-pruned exact KNN, round 18.
//
// Round-17 post-mortem: work-stealing spin tail caused a device-atomic
// polling storm (4096 waves RMW-polling) that backed up the L2/fabric and
// slowed the producers -> phase1 104us.  Reverted.
// This round: SINGLE COOPERATIVE KERNEL (hipLaunchCooperativeKernel, which
// the harness supports) — pack / scan / scatter / phase1 / phase2 separated
// by grid.sync() instead of 5 launch boundaries.  No polling anywhere:
// phase2's work count is final after the barrier.  Phase internals are the
// verified r16 versions.  If the cooperative launch errors out, fall back
// to the r16 5-kernel pipeline (verified, ~118us).

constexpr int NPTS  = 8192;
constexpr int NB    = 2;
constexpr int KNN   = 10;
constexpr int QPB   = 64;               // fallback kernel's queries/block
constexpr int WPB   = 16;               // phase1 slices per query
constexpr int NBLK  = 1024;             // fused grid: 4 blocks/CU co-resident
constexpr int MASK13 = 0xFFFFE000;

constexpr int   G    = 32;
constexpr int   NC   = G * G * G;
constexpr float BMIN = -5.5f;
constexpr float BW   = 11.0f;
constexpr float H    = BW / G;          // 0.34375
constexpr float INVH = (float)G / BW;

// ---------------- selection helpers ----------------
__device__ __forceinline__ void ins1(int l[KNN], int x) {
#pragma unroll
    for (int k = KNN - 1; k > 0; --k) l[k] = min(l[k], max(l[k - 1], x));
    l[0] = min(l[0], x);
}
__device__ __forceinline__ void ins2(int l[KNN], int a, int b) {
    const int b0 = min(a, b), b1 = max(a, b);
#pragma unroll
    for (int k = KNN - 1; k >= 2; --k)
        l[k] = min(l[k], min(max(l[k - 1], b0), max(l[k - 2], b1)));
    l[1] = min(l[1], min(max(l[0], b0), b1));
    l[0] = min(l[0], b0);
}
template<int S>
__device__ __forceinline__ void ins2s(int l[KNN], int a, int b) {
    const int b0 = min(a, b), b1 = max(a, b);
#pragma unroll
    for (int k = KNN - 1; k >= S + 2; --k)
        l[k] = min(l[k], min(max(l[k - 1], b0), max(l[k - 2], b1)));
    l[S + 1] = min(l[S + 1], min(max(l[S], b0), b1));
    l[S] = min(l[S], b0);
}
__device__ __forceinline__ void merge_sorted(int l[KNN], const int p[KNN]) {
    ins2s<0>(l, p[0], p[1]);
    ins2s<2>(l, p[2], p[3]);
    ins2s<4>(l, p[4], p[5]);
    ins2s<6>(l, p[6], p[7]);
    ins2s<8>(l, p[8], p[9]);
}

// ---------------- shared phase-1 scan body ----------------
template<int S>
__device__ __forceinline__ void scan_batched(const float4* __restrict__ W,
                                             const int* __restrict__ st,
                                             int cx, int cy, int cz,
                                             float m2x, float m2y, float m2z,
                                             float q2, int qpos, int sl,
                                             int l[KNN])
{
    constexpr int Wd = 2 * S + 1;
    constexpr int R  = Wd * Wd;
    constexpr int CH = 5;               // prime-chunk width
    const int IMAX = 0x7FFFFFFF;
    int J0[R], J1[R];
#pragma unroll
    for (int r = 0; r < R; ++r) {
        const int dy = r % Wd - S, dz = r / Wd - S;   // compile-time
        const int ay = cy + dy, az = cz + dz;
        const bool ok = ((unsigned)ay < G) && ((unsigned)az < G);
        const int cbase = (az << 10) | (ay << 5);
        const int lo = cbase + max(cx - S, 0);
        const int hi = cbase + min(cx + S, G - 1) + 1;
        J0[r] = ok ? st[lo] : 0;                      // group-broadcast loads
        J1[r] = ok ? st[hi] : 0;
    }
#pragma unroll
    for (int base = 0; base < R; base += CH) {
        float4 P[CH];
#pragma unroll
        for (int c = 0; c < CH; ++c) {
            const int r = base + c;                   // compile-time
            if (r < R) {
                const int j = min(J0[r] + sl, NPTS - 1);  // clamped, harmless
                P[c] = W[j];                          // 16 consecutive float4
            }
        }
#pragma unroll
        for (int c = 0; c < CH; ++c) {
            const int r = base + c;
            if (r < R) {
                const int j1 = J1[r];
                int j = J0[r] + sl;
                if (j < j1) {
                    float4 c4 = P[c];                 // primed, in flight
                    while (true) {
                        const int jn = j + WPB;
                        const bool more = jn < j1;
                        float4 nx;
                        if (more) nx = W[jn];         // prefetch next (contig)
                        const float d2 = fmaf(m2x, c4.x,
                                         fmaf(m2y, c4.y,
                                         fmaf(m2z, c4.z, c4.w + q2)));
                        int key = (__float_as_int(d2) & MASK13) | j;
                        key = (j == qpos) ? IMAX : key;
                        ins1(l, key);
                        if (!more) break;
                        c4 = nx; j = jn;
                    }
                }
            }
        }
    }
}

// ================= fused cooperative kernel =================
__global__ __launch_bounds__(256, 4)
void fused_all(const float* __restrict__ p1, const float* __restrict__ p2,
               float4* __restrict__ w, int* __restrict__ hist,
               int* __restrict__ starts, int* __restrict__ cellof,
               float4* __restrict__ wsorted, float4* __restrict__ p2s,
               float* __restrict__ out, int* __restrict__ nfail,
               int* __restrict__ worklist)
{
    cg::grid_group grid = cg::this_grid();
    __shared__ int   shi[4];
    __shared__ float shf[4];

    const int tid  = threadIdx.x;
    const int bid  = blockIdx.x;
    const int gtid = (bid << 8) + tid;
    const int lane = tid & 63;
    const int wvid = tid >> 6;
    const int IMAX = 0x7FFFFFFF;
    const float SCALE = 1.0f / (float)(NB * NPTS * 3);

    // ---- A: pack/bin (hist pre-zeroed by the on-stream memset) ----
    if (gtid < NB * NPTS) {
        if (gtid == 0) { atomicExch(nfail, 0); atomicExch(out, 0.0f); }
        const int i = gtid;
        const float x = p1[3 * i], y = p1[3 * i + 1], z = p1[3 * i + 2];
        w[i] = make_float4(x, y, z, fmaf(x, x, fmaf(y, y, z * z)));
        const int cx = min(max((int)floorf((x - BMIN) * INVH), 0), G - 1);
        const int cy = min(max((int)floorf((y - BMIN) * INVH), 0), G - 1);
        const int cz = min(max((int)floorf((z - BMIN) * INVH), 0), G - 1);
        const int c = (cz << 10) | (cy << 5) | cx;
        cellof[i] = c;
        atomicAdd(&hist[(i >> 13) * NC + c], 1);
    }
    grid.sync();

    // ---- B: per-batch prefix scan, blocks 0 and 1, two passes ----
    if (bid < NB) {
        const int* hb = hist + bid * NC;
        const int c0 = tid << 7;               // 128 cells/thread
        const int4* hb4 = (const int4*)(hb + c0);
        int sum = 0;
#pragma unroll
        for (int j = 0; j < 32; ++j) {
            const int4 v = hb4[j];
            sum += v.x + v.y + v.z + v.w;
        }
        int incl = sum;
#pragma unroll
        for (int off = 1; off < 64; off <<= 1) {
            const int u = __shfl_up(incl, off);
            if (lane >= off) incl += u;
        }
        if (lane == 63) shi[wvid] = incl;
        __syncthreads();
        int woff = 0;
        for (int e = 0; e < wvid; ++e) woff += shi[e];
        int run = woff + incl - sum;           // exclusive prefix at c0
        int* sb = starts + bid * (NC + 1);
#pragma unroll 4
        for (int j = 0; j < 32; ++j) {         // pass 2: re-read (L2-hot)
            const int4 v = hb4[j];
            sb[c0 + 4 * j    ] = run; run += v.x;
            sb[c0 + 4 * j + 1] = run; run += v.y;
            sb[c0 + 4 * j + 2] = run; run += v.z;
            sb[c0 + 4 * j + 3] = run; run += v.w;
        }
        if (tid == 255) sb[NC] = run;
    }
    grid.sync();

    // ---- C: scatter into cell order ----
    if (gtid < NB * NPTS) {
        const int i = gtid;
        const int b = i >> 13;
        const int c = cellof[i];
        const int old = atomicSub(&hist[b * NC + c], 1);
        const int pos = b * NPTS + starts[b * (NC + 1) + c] + old - 1;
        wsorted[pos] = w[i];
        p2s[pos] = make_float4(p2[3 * i], p2[3 * i + 1], p2[3 * i + 2], 0.0f);
    }
    grid.sync();

    // ---- D: phase1 (r16 strided map + butterfly merge) ----
    {
        const int sl = tid & 15;
        const int gw = (tid >> 4) & 3;
        const int wglob = wvid * NBLK + bid;
        const int unit  = (wglob << 2) | gw;
        const int batch = unit & 1;
        const int qpos  = unit >> 1;

        const float4* W  = wsorted + batch * NPTS;
        const float4* P2 = p2s + batch * NPTS;
        const int*    st = starts + batch * (NC + 1);

        const float4 qp = W[qpos];
        const int cx = min(max((int)floorf((qp.x - BMIN) * INVH), 0), G - 1);
        const int cy = min(max((int)floorf((qp.y - BMIN) * INVH), 0), G - 1);
        const int cz = min(max((int)floorf((qp.z - BMIN) * INVH), 0), G - 1);
        const float lox = BMIN + cx * H, loy = BMIN + cy * H, loz = BMIN + cz * H;
        const float df = fminf(fminf(fminf(qp.x - lox, lox + H - qp.x),
                                     fminf(qp.y - loy, loy + H - qp.y)),
                               fminf(qp.z - loz, loz + H - qp.z));
        const float m2x = -2.0f * qp.x, m2y = -2.0f * qp.y, m2z = -2.0f * qp.z;
        const float q2 = qp.w;
        const int sCov = (q2 > 4.8f) ? 2 : 1;

        int l[KNN];
#pragma unroll
        for (int k = 0; k < KNN; ++k) l[k] = IMAX;

        if (sCov == 1)
            scan_batched<1>(W, st, cx, cy, cz, m2x, m2y, m2z, q2, qpos, sl, l);
        else
            scan_batched<2>(W, st, cx, cy, cz, m2x, m2y, m2z, q2, qpos, sl, l);

#pragma unroll
        for (int off = 1; off < WPB; off <<= 1) {
            int p[KNN];
#pragma unroll
            for (int k = 0; k < KNN; ++k) p[k] = __shfl_xor(l[k], off);
            merge_sorted(l, p);
        }

        float v = 0.0f;
        if (sl == 0) {
            const float tau = __int_as_float(l[KNN - 1] & MASK13);
            const float R = (float)sCov * H + df;
            const bool covered = (tau <= R * R * 0.996f);
            if (covered) {
                float s1x = 0, s1y = 0, s1z = 0, s2x = 0, s2y = 0, s2z = 0;
#pragma unroll
                for (int k = 0; k < KNN; ++k) {
                    const int j = l[k] & (NPTS - 1);
                    const float4 c4 = W[j];
                    const float4 n2 = P2[j];
                    s1x += c4.x; s1y += c4.y; s1z += c4.z;
                    s2x += n2.x; s2y += n2.y; s2z += n2.z;
                }
                const float4 p2v = P2[qpos];
                const float dx  = (s1x * 0.1f - qp.x) - (s2x * 0.1f - p2v.x);
                const float dy2 = (s1y * 0.1f - qp.y) - (s2y * 0.1f - p2v.y);
                const float dz2 = (s1z * 0.1f - qp.z) - (s2z * 0.1f - p2v.z);
                v = fabsf(dx) + fabsf(dy2) + fabsf(dz2);
            } else {
                const int wi = atomicAdd(nfail, 1);
                atomicExch(&worklist[wi], (batch << 16) | qpos);
            }
        }
#pragma unroll
        for (int off = 32; off >= 1; off >>= 1) v += __shfl_down(v, off);
        if (lane == 0) shf[wvid] = v;
        __syncthreads();
        if (tid == 0) {
            const float s = shf[0] + shf[1] + shf[2] + shf[3];
            if (s != 0.0f) atomicAdd(out, s * SCALE);
        }
    }
    grid.sync();

    // ---- E: phase2, wave-per-item over the (now final) worklist ----
    {
        int nf;
        if (lane == 0) nf = atomicAdd(nfail, 0);
        nf = __shfl(nf, 0);
        const int gwv = (bid << 2) + wvid;        // 0..4095
        float acc = 0.0f;
        for (int i = gwv; i < nf; i += NBLK * 4) {
            int e;
            if (lane == 0) e = atomicAdd(&worklist[i], 0);
            e = __shfl(e, 0);
            const int sbatch = e >> 16, sq = e & 0xFFFF;
            const float4* SW  = wsorted + sbatch * NPTS;
            const float4* SP2 = p2s + sbatch * NPTS;
            const float4 sqp = SW[sq];
            const float m2x = -2.0f * sqp.x, m2y = -2.0f * sqp.y, m2z = -2.0f * sqp.z;
            const float sq2 = sqp.w;

            int l2[KNN];
#pragma unroll
            for (int k = 0; k < KNN; ++k) l2[k] = IMAX;
#pragma unroll 2
            for (int it = 0; it < NPTS / 128; ++it) {
                const int ja = it * 128 + lane, jb = ja + 64;
                const float4 ca = SW[ja];
                const float4 cb = SW[jb];
                const float da = fmaf(m2x, ca.x, fmaf(m2y, ca.y, fmaf(m2z, ca.z, ca.w + sq2)));
                const float db = fmaf(m2x, cb.x, fmaf(m2y, cb.y, fmaf(m2z, cb.z, cb.w + sq2)));
                int ka = (__float_as_int(da) & MASK13) | ja;
                int kb = (__float_as_int(db) & MASK13) | jb;
                ka = (ja == sq) ? IMAX : ka;
                kb = (jb == sq) ? IMAX : kb;
                ins2(l2, ka, kb);
            }
            for (int off = 1; off < 64; off <<= 1) {
                int p[KNN];
#pragma unroll
                for (int k = 0; k < KNN; ++k) p[k] = __shfl_xor(l2[k], off);
                merge_sorted(l2, p);
            }
            float s1x = 0, s1y = 0, s1z = 0, s2x = 0, s2y = 0, s2z = 0;
#pragma unroll
            for (int k = 0; k < KNN; ++k) {
                const int j = l2[k] & (NPTS - 1);
                const float4 c4 = SW[j];
                const float4 n2 = SP2[j];
                s1x += c4.x; s1y += c4.y; s1z += c4.z;
                s2x += n2.x; s2y += n2.y; s2z += n2.z;
            }
            const float4 p2v = SP2[sq];
            const float dx = (s1x * 0.1f - sqp.x) - (s2x * 0.1f - p2v.x);
            const float dy = (s1y * 0.1f - sqp.y) - (s2y * 0.1f - p2v.y);
            const float dz = (s1z * 0.1f - sqp.z) - (s2z * 0.1f - p2v.z);
            if (lane == 0) acc += fabsf(dx) + fabsf(dy) + fabsf(dz);
        }
        if (lane == 0 && acc != 0.0f)
            atomicAdd(out, acc * SCALE);
    }
}

// ================= fallback pipeline (r16, verified) =================
__global__ void pack_bin(const float* __restrict__ p1, float4* __restrict__ w,
                         int* __restrict__ hist, int* __restrict__ cellof,
                         float* __restrict__ out, int* __restrict__ nfail) {
    const int i = blockIdx.x * blockDim.x + threadIdx.x;
    if (i >= NB * NPTS) return;
    if (i == 0) { out[0] = 0.0f; nfail[0] = 0; }
    const float x = p1[3 * i], y = p1[3 * i + 1], z = p1[3 * i + 2];
    w[i] = make_float4(x, y, z, fmaf(x, x, fmaf(y, y, z * z)));
    const int cx = min(max((int)floorf((x - BMIN) * INVH), 0), G - 1);
    const int cy = min(max((int)floorf((y - BMIN) * INVH), 0), G - 1);
    const int cz = min(max((int)floorf((z - BMIN) * INVH), 0), G - 1);
    const int c = (cz << 10) | (cy << 5) | cx;
    cellof[i] = c;
    atomicAdd(&hist[(i >> 13) * NC + c], 1);
}

__global__ __launch_bounds__(1024)
void scan_cells(const int* __restrict__ hist, int* __restrict__ starts) {
    __shared__ int wsum[16];
    const int b = blockIdx.x, t = threadIdx.x;
    const int* hb = hist + b * NC;
    int* sb = starts + b * (NC + 1);
    const int c0 = t * 32;
    const int4* hb4 = (const int4*)(hb + c0);
    int loc[32]; int sum = 0;
#pragma unroll
    for (int j = 0; j < 8; ++j) {
        const int4 v = hb4[j];
        loc[4 * j + 0] = v.x; loc[4 * j + 1] = v.y;
        loc[4 * j + 2] = v.z; loc[4 * j + 3] = v.w;
        sum += v.x + v.y + v.z + v.w;
    }
    const int lane = t & 63, wvi = t >> 6;
    int incl = sum;
#pragma unroll
    for (int off = 1; off < 64; off <<= 1) {
        const int v = __shfl_up(incl, off);
        if (lane >= off) incl += v;
    }
    if (lane == 63) wsum[wvi] = incl;
    __syncthreads();
    if (t < 16) {
        const int v = wsum[t];
        int iv = v;
#pragma unroll
        for (int off = 1; off < 16; off <<= 1) {
            const int u = __shfl_up(iv, off);
            if (t >= off) iv += u;
        }
        wsum[t] = iv - v;
    }
    __syncthreads();
    int run = wsum[wvi] + incl - sum;
#pragma unroll
    for (int j = 0; j < 32; ++j) { sb[c0 + j] = run; run += loc[j]; }
    if (t == 1023) sb[NC] = run;
}

__global__ void scatter_all(const int* __restrict__ cellof,
                            const int* __restrict__ starts,
                            int* __restrict__ hist,
                            const float4* __restrict__ w,
                            const float* __restrict__ p2,
                            float4* __restrict__ wsorted,
                            float4* __restrict__ p2s) {
    const int i = blockIdx.x * blockDim.x + threadIdx.x;
    if (i >= NB * NPTS) return;
    const int b = i >> 13;
    const int c = cellof[i];
    const int old = atomicSub(&hist[b * NC + c], 1);
    const int pos = b * NPTS + starts[b * (NC + 1) + c] + old - 1;
    wsorted[pos] = w[i];
    p2s[pos] = make_float4(p2[3 * i], p2[3 * i + 1], p2[3 * i + 2], 0.0f);
}

__global__ __launch_bounds__(256)
void phase1_sa(const float4* __restrict__ wsorted, const float4* __restrict__ p2s,
               const int* __restrict__ starts, float* __restrict__ out,
               int* __restrict__ nfail, int* __restrict__ worklist)
{
    __shared__ float red[4];
    const int tid = threadIdx.x;
    const int sl  = tid & 15;
    const int gw  = (tid >> 4) & 3;
    const int wv  = tid >> 6;
    const int wglob = wv * NBLK + blockIdx.x;
    const int unit  = (wglob << 2) | gw;
    const int batch = unit & 1;
    const int qpos  = unit >> 1;

    const float4* W  = wsorted + batch * NPTS;
    const float4* P2 = p2s + batch * NPTS;
    const int*    st = starts + batch * (NC + 1);

    const float4 qp = W[qpos];
    const int cx = min(max((int)floorf((qp.x - BMIN) * INVH), 0), G - 1);
    const int cy = min(max((int)floorf((qp.y - BMIN) * INVH), 0), G - 1);
    const int cz = min(max((int)floorf((qp.z - BMIN) * INVH), 0), G - 1);
    const float lox = BMIN + cx * H, loy = BMIN + cy * H, loz = BMIN + cz * H;
    const float df = fminf(fminf(fminf(qp.x - lox, lox + H - qp.x),
                                 fminf(qp.y - loy, loy + H - qp.y)),
                           fminf(qp.z - loz, loz + H - qp.z));
    const float m2x = -2.0f * qp.x, m2y = -2.0f * qp.y, m2z = -2.0f * qp.z;
    const float q2 = qp.w;
    const int IMAX = 0x7FFFFFFF;
    const int sCov = (q2 > 4.8f) ? 2 : 1;

    int l[KNN];
#pragma unroll
    for (int k = 0; k < KNN; ++k) l[k] = IMAX;

    if (sCov == 1)
        scan_batched<1>(W, st, cx, cy, cz, m2x, m2y, m2z, q2, qpos, sl, l);
    else
        scan_batched<2>(W, st, cx, cy, cz, m2x, m2y, m2z, q2, qpos, sl, l);

#pragma unroll
    for (int off = 1; off < WPB; off <<= 1) {
        int p[KNN];
#pragma unroll
        for (int k = 0; k < KNN; ++k) p[k] = __shfl_xor(l[k], off);
        merge_sorted(l, p);
    }

    float v = 0.0f;
    if (sl == 0) {
        const float tau = __int_as_float(l[KNN - 1] & MASK13);
        const float R = (float)sCov * H + df;
        const bool covered = (tau <= R * R * 0.996f);
        if (covered) {
            float s1x = 0, s1y = 0, s1z = 0, s2x = 0, s2y = 0, s2z = 0;
#pragma unroll
            for (int k = 0; k < KNN; ++k) {
                const int j = l[k] & (NPTS - 1);
                const float4 c4 = W[j];
                const float4 n2 = P2[j];
                s1x += c4.x; s1y += c4.y; s1z += c4.z;
                s2x += n2.x; s2y += n2.y; s2z += n2.z;
            }
            const float4 p2v = P2[qpos];
            const float dx  = (s1x * 0.1f - qp.x) - (s2x * 0.1f - p2v.x);
            const float dy2 = (s1y * 0.1f - qp.y) - (s2y * 0.1f - p2v.y);
            const float dz2 = (s1z * 0.1f - qp.z) - (s2z * 0.1f - p2v.z);
            v = fabsf(dx) + fabsf(dy2) + fabsf(dz2);
        } else {
            const int wi = atomicAdd(nfail, 1);
            worklist[wi] = (batch << 16) | qpos;
        }
    }
#pragma unroll
    for (int off = 32; off >= 1; off >>= 1) v += __shfl_down(v, off);
    const int lane = tid & 63;
    if (lane == 0) red[wv] = v;
    __syncthreads();
    if (tid == 0) {
        const float s = red[0] + red[1] + red[2] + red[3];
        if (s != 0.0f)
            atomicAdd(out, s * (1.0f / (float)(NB * NPTS * 3)));
    }
}

constexpr int P2BLK = 256;
constexpr int P2GRID = 512;

__global__ __launch_bounds__(P2BLK)
void phase2(const float4* __restrict__ wsorted, const float4* __restrict__ p2s,
            const int* __restrict__ nfail, const int* __restrict__ worklist,
            float* __restrict__ out)
{
    const int lane = threadIdx.x & 63;
    const int wv   = threadIdx.x >> 6;
    const int wid  = blockIdx.x * (P2BLK / 64) + wv;
    const int NW   = P2GRID * (P2BLK / 64);
    const int nf   = *nfail;
    const int IMAX = 0x7FFFFFFF;
    float acc = 0.0f;

    for (int i = wid; i < nf; i += NW) {
        const int e = worklist[i];
        const int batch = e >> 16, qpos = e & 0xFFFF;
        const float4* W  = wsorted + batch * NPTS;
        const float4* P2 = p2s + batch * NPTS;
        const float4 qp = W[qpos];
        const float m2x = -2.0f * qp.x, m2y = -2.0f * qp.y, m2z = -2.0f * qp.z;
        const float q2 = qp.w;

        int l[KNN];
#pragma unroll
        for (int k = 0; k < KNN; ++k) l[k] = IMAX;
#pragma unroll 2
        for (int it = 0; it < NPTS / 128; ++it) {
            const int ja = it * 128 + lane, jb = ja + 64;
            const float4 ca = W[ja];
            const float4 cb = W[jb];
            const float da = fmaf(m2x, ca.x, fmaf(m2y, ca.y, fmaf(m2z, ca.z, ca.w + q2)));
            const float db = fmaf(m2x, cb.x, fmaf(m2y, cb.y, fmaf(m2z, cb.z, cb.w + q2)));
            int ka = (__float_as_int(da) & MASK13) | ja;
            int kb = (__float_as_int(db) & MASK13) | jb;
            ka = (ja == qpos) ? IMAX : ka;
            kb = (jb == qpos) ? IMAX : kb;
            ins2(l, ka, kb);
        }
        for (int off = 1; off < 64; off <<= 1) {
            int p[KNN];
#pragma unroll
            for (int k = 0; k < KNN; ++k) p[k] = __shfl_xor(l[k], off);
            merge_sorted(l, p);
        }
        float s1x = 0, s1y = 0, s1z = 0, s2x = 0, s2y = 0, s2z = 0;
#pragma unroll
        for (int k = 0; k < KNN; ++k) {
            const int j = l[k] & (NPTS - 1);
            const float4 c4 = W[j];
            const float4 n2 = P2[j];
            s1x += c4.x; s1y += c4.y; s1z += c4.z;
            s2x += n2.x; s2y += n2.y; s2z += n2.z;
        }
        const float4 p2v = P2[qpos];
        const float dx = (s1x * 0.1f - qp.x) - (s2x * 0.1f - p2v.x);
        const float dy = (s1y * 0.1f - qp.y) - (s2y * 0.1f - p2v.y);
        const float dz = (s1z * 0.1f - qp.z) - (s2z * 0.1f - p2v.z);
        if (lane == 0) acc += fabsf(dx) + fabsf(dy) + fabsf(dz);
    }

    if (lane == 0 && acc != 0.0f)
        atomicAdd(out, acc * (1.0f / (float)(NB * NPTS * 3)));
}

// ---------------- tiny-workspace fallback (O(N^2), verified) ----------------
constexpr int FB_WPB = 8;
constexpr int FB_BLOCK = QPB * FB_WPB;  // 512
constexpr int CHUNK = NPTS / FB_WPB;

__global__ void prep_pack(const float* __restrict__ p, float4* __restrict__ w) {
    const int i = blockIdx.x * blockDim.x + threadIdx.x;
    if (i < NB * NPTS) {
        const float x = p[3 * i], y = p[3 * i + 1], z = p[3 * i + 2];
        w[i] = make_float4(x, y, z, fmaf(x, x, fmaf(y, y, z * z)));
    }
}

__global__ __launch_bounds__(FB_BLOCK, 2)
void knn_lap(const float4* __restrict__ w1, const float* __restrict__ p2,
             float* __restrict__ out)
{
    __shared__ int mv[FB_WPB * KNN * QPB];
    const int batch = blockIdx.x >> 7;
    const int qbase = (blockIdx.x & 127) << 6;
    const int lane  = threadIdx.x & 63;
    const int wv    = __builtin_amdgcn_readfirstlane(threadIdx.x >> 6);
    const int query = qbase + lane;
    const float4* Wb = w1 + batch * NPTS;
    const float4 qp = Wb[query];
    const float m2x = -2.0f * qp.x, m2y = -2.0f * qp.y, m2z = -2.0f * qp.z;
    const float q2 = qp.w;
    const int IMAX = 0x7FFFFFFF;
    int l[KNN];
#pragma unroll
    for (int k = 0; k < KNN; ++k) l[k] = IMAX;
    const int c0 = wv * CHUNK;
    const float4* cand = Wb + c0;
#pragma unroll 4
    for (int i = 0; i < CHUNK; i += 2) {
        const float4 ca = cand[i];
        const float4 cb = cand[i + 1];
        const int ja = c0 + i, jb = ja + 1;
        const float da = fmaf(m2x, ca.x, fmaf(m2y, ca.y, fmaf(m2z, ca.z, ca.w + q2)));
        const float db = fmaf(m2x, cb.x, fmaf(m2y, cb.y, fmaf(m2z, cb.z, cb.w + q2)));
        int ka = (__float_as_int(da) & MASK13) | ja;
        int kb = (__float_as_int(db) & MASK13) | jb;
        ka = (ja == query) ? IMAX : ka;
        kb = (jb == query) ? IMAX : kb;
        ins2(l, ka, kb);
    }
#pragma unroll
    for (int k = 0; k < KNN; ++k) mv[(wv * KNN + k) * QPB + lane] = l[k];
    __syncthreads();
    if (threadIdx.x < QPB) {
        int m[KNN];
#pragma unroll
        for (int k = 0; k < KNN; ++k) m[k] = IMAX;
#pragma unroll
        for (int e = 0; e < FB_WPB; ++e) {
            int p[KNN];
#pragma unroll
            for (int k = 0; k < KNN; ++k) p[k] = mv[(e * KNN + k) * QPB + lane];
            merge_sorted(m, p);
        }
        const float* P2b = p2 + (size_t)batch * NPTS * 3;
        float s1x = 0, s1y = 0, s1z = 0, s2x = 0, s2y = 0, s2z = 0;
#pragma unroll
        for (int k = 0; k < KNN; ++k) {
            const int j = m[k] & (NPTS - 1);
            const float4 c = Wb[j];
            s1x += c.x; s1y += c.y; s1z += c.z;
            s2x += P2b[3 * j + 0]; s2y += P2b[3 * j + 1]; s2z += P2b[3 * j + 2];
        }
        const int q = qbase + threadIdx.x;
        const float p2x = P2b[3 * q + 0], p2y = P2b[3 * q + 1], p2z = P2b[3 * q + 2];
        const float dx = (s1x * 0.1f - qp.x) - (s2x * 0.1f - p2x);
        const float dy = (s1y * 0.1f - qp.y) - (s2y * 0.1f - p2y);
        const float dz = (s1z * 0.1f - qp.z) - (s2z * 0.1f - p2z);
        float v = fabsf(dx) + fabsf(dy) + fabsf(dz);
#pragma unroll
        for (int off = 32; off >= 1; off >>= 1) v += __shfl_down(v, off);
        if (threadIdx.x == 0)
            atomicAdd(out, v * (1.0f / (float)(NB * NPTS * 3)));
    }
}

// ---------------- launcher ----------------
extern "C" void kernel_launch(void* const* d_in, const int* in_sizes, int n_in,
                              void* d_out, int out_size, void* d_ws, size_t ws_size,
                              hipStream_t stream) {
    const float* p1 = (const float*)d_in[0];
    const float* p2 = (const float*)d_in[1];
    float* out = (float*)d_out;

    size_t off = 0;
    float4* w       = (float4*)d_ws;               off += (size_t)NB * NPTS * 16;
    int*    hist    = (int*)((char*)d_ws + off);   off += (size_t)NB * NC * 4;
    int*    starts  = (int*)((char*)d_ws + off);   off += (size_t)NB * (NC + 1) * 4 + 8;
    int*    cellof  = (int*)((char*)d_ws + off);   off += (size_t)NB * NPTS * 4;
    float4* wsorted = (float4*)((char*)d_ws + off); off += (size_t)NB * NPTS * 16;
    float4* p2s     = (float4*)((char*)d_ws + off); off += (size_t)NB * NPTS * 16;
    int*    nfail   = (int*)((char*)d_ws + off);   off += 512;
    int*    worklist= (int*)((char*)d_ws + off);   off += (size_t)NB * NPTS * 4;

    if (ws_size < off) {  // tiny workspace: brute force
        hipMemsetAsync(out, 0, sizeof(float), stream);
        prep_pack<<<(NB * NPTS + 255) / 256, 256, 0, stream>>>(p1, w);
        knn_lap<<<NB * (NPTS / QPB), FB_BLOCK, 0, stream>>>(w, p2, out);
        return;
    }

    hipMemsetAsync(hist, 0, (size_t)NB * NC * 4, stream);

    void* kargs[] = { (void*)&p1, (void*)&p2, (void*)&w, (void*)&hist,
                      (void*)&starts, (void*)&cellof, (void*)&wsorted,
                      (void*)&p2s, (void*)&out, (void*)&nfail,
                      (void*)&worklist };
    const hipError_t err = hipLaunchCooperativeKernel(
        (const void*)fused_all, dim3(NBLK), dim3(256), kargs, 0, stream);

    if (err != hipSuccess) {   // capture/occupancy rejection: r16 pipeline
        pack_bin<<<(NB * NPTS + 255) / 256, 256, 0, stream>>>(p1, w, hist,
                                                              cellof, out, nfail);
        scan_cells<<<NB, 1024, 0, stream>>>(hist, starts);
        scatter_all<<<(NB * NPTS + 255) / 256, 256, 0, stream>>>(cellof, starts,
                                                                 hist, w, p2,
                                                                 wsorted, p2s);
        phase1_sa<<<NBLK, 256, 0, stream>>>(wsorted, p2s, starts, out,
                                            nfail, worklist);
        phase2<<<P2GRID, P2BLK, 0, stream>>>(wsorted, p2s, nfail, worklist, out);
    }
}

// Round 9
// 118.173 us; speedup vs baseline: 4.2596x; 4.2596x over previous
//
#include <hip/hip_runtime.h>
#include <math.h>

// PointLaplacianLoss — grid-pruned exact KNN, round 19.
//
// Round-17/18 post-mortems: device-scope spinning (work-steal polls, coop
// grid.sync) is catastrophic on this chip (171us / 503us).  The launch-gap
// budget (~25us over 6 dispatches) must be cut with ORDINARY kernels.
// This round: the build pipeline is batch-local end-to-end, so ONE kernel
// with one 1024-thread block per batch replaces memset+pack+scan+scatter
// (4 dispatches -> 1, no cross-block sync at all):
//   * hist+cursor in LDS (128 KB/block, m201 precedent), XOR-swizzled
//     idx = c ^ ((c>>5)&31) to kill the stride-32 64-way bank conflict.
//   * pack keeps the 8 points/thread in registers; scatter re-uses them.
//   * out/nfail zeroed here; starts[] written to global for phase1.
// phase1/phase2 are the verified round-14 versions (116.3us), unchanged.
// Dispatches: build_all, phase1, phase2 = 3.

constexpr int NPTS  = 8192;
constexpr int NB    = 2;
constexpr int KNN   = 10;
constexpr int QPB   = 64;               // fallback kernel's queries/block
constexpr int WPB   = 16;               // phase1 slices per query (stride)
constexpr int P1Q     = 32;             // phase1 queries per block
constexpr int P1BLOCK = P1Q * WPB;      // 512 threads: one per (query,slice)
constexpr int MVSTR   = WPB * KNN + 1;  // 161: padded per-query LDS stride
constexpr int MASK13 = 0xFFFFE000;

constexpr int   G    = 32;
constexpr int   NC   = G * G * G;
constexpr float BMIN = -5.5f;
constexpr float BW   = 11.0f;
constexpr float H    = BW / G;          // 0.34375
constexpr float INVH = (float)G / BW;

__device__ __forceinline__ int SW(int c) { return c ^ ((c >> 5) & 31); }

// ---------------- selection helpers ----------------
__device__ __forceinline__ void ins1(int l[KNN], int x) {
#pragma unroll
    for (int k = KNN - 1; k > 0; --k) l[k] = min(l[k], max(l[k - 1], x));
    l[0] = min(l[0], x);
}
__device__ __forceinline__ void ins2(int l[KNN], int a, int b) {
    const int b0 = min(a, b), b1 = max(a, b);
#pragma unroll
    for (int k = KNN - 1; k >= 2; --k)
        l[k] = min(l[k], min(max(l[k - 1], b0), max(l[k - 2], b1)));
    l[1] = min(l[1], min(max(l[0], b0), b1));
    l[0] = min(l[0], b0);
}
template<int S>
__device__ __forceinline__ void ins2s(int l[KNN], int a, int b) {
    const int b0 = min(a, b), b1 = max(a, b);
#pragma unroll
    for (int k = KNN - 1; k >= S + 2; --k)
        l[k] = min(l[k], min(max(l[k - 1], b0), max(l[k - 2], b1)));
    l[S + 1] = min(l[S + 1], min(max(l[S], b0), b1));
    l[S] = min(l[S], b0);
}
__device__ __forceinline__ void merge_sorted(int l[KNN], const int p[KNN]) {
    ins2s<0>(l, p[0], p[1]);
    ins2s<2>(l, p[2], p[3]);
    ins2s<4>(l, p[4], p[5]);
    ins2s<6>(l, p[6], p[7]);
    ins2s<8>(l, p[8], p[9]);
}

// ---------------- fused build: zero+pack+bin+scan+scatter ----------------
// One block per batch; everything batch-local; only __syncthreads needed.
constexpr int BB = 1024;                 // threads; 8 points/thread
constexpr int PPT = NPTS / BB;           // 8

__global__ __launch_bounds__(BB)
void build_all(const float* __restrict__ p1, const float* __restrict__ p2,
               int* __restrict__ starts, float4* __restrict__ wsorted,
               float4* __restrict__ p2s, float* __restrict__ out,
               int* __restrict__ nfail)
{
    __shared__ unsigned int hcur[NC];    // 128 KB: hist, then cursor
    __shared__ int wsum[BB / 64];

    const int b = blockIdx.x;            // batch
    const int t = threadIdx.x;
    if (b == 0 && t == 0) { out[0] = 0.0f; nfail[0] = 0; }

    // zero hist (transposed index: conflict-free)
#pragma unroll
    for (int j = 0; j < NC / BB; ++j) hcur[t + BB * j] = 0u;
    __syncthreads();

    // ---- pack + bin: 8 consecutive points per thread, kept in registers ----
    const float* P1 = p1 + (size_t)b * NPTS * 3;
    float4 r[6];
    {
        const float4* P14 = (const float4*)P1;
#pragma unroll
        for (int j = 0; j < 6; ++j) r[j] = P14[t * 6 + j];   // 24 floats
    }
    const float* rf = (const float*)r;
    float px[PPT], py[PPT], pz[PPT], pw[PPT]; int pc[PPT];
#pragma unroll
    for (int j = 0; j < PPT; ++j) {
        const float x = rf[3 * j], y = rf[3 * j + 1], z = rf[3 * j + 2];
        px[j] = x; py[j] = y; pz[j] = z;
        pw[j] = fmaf(x, x, fmaf(y, y, z * z));
        const int cx = min(max((int)floorf((x - BMIN) * INVH), 0), G - 1);
        const int cy = min(max((int)floorf((y - BMIN) * INVH), 0), G - 1);
        const int cz = min(max((int)floorf((z - BMIN) * INVH), 0), G - 1);
        pc[j] = (cz << 10) | (cy << 5) | cx;
        atomicAdd(&hcur[SW(pc[j])], 1u);
    }
    __syncthreads();

    // ---- scan: 32 consecutive cells per thread ----
    const int c0 = t * 32;
    unsigned int sum = 0;
#pragma unroll
    for (int j = 0; j < 32; ++j) sum += hcur[SW(c0 + j)];
    const int lane = t & 63, wvi = t >> 6;
    unsigned int incl = sum;
#pragma unroll
    for (int off = 1; off < 64; off <<= 1) {
        const unsigned int u = __shfl_up(incl, off);
        if (lane >= off) incl += u;
    }
    if (lane == 63) wsum[wvi] = (int)incl;
    __syncthreads();
    unsigned int woff = 0;
    for (int e = 0; e < wvi; ++e) woff += (unsigned int)wsum[e];
    unsigned int run = woff + incl - sum;         // exclusive prefix at c0
    int* sb = starts + b * (NC + 1);
#pragma unroll
    for (int j = 0; j < 32; ++j) {
        const unsigned int cnt = hcur[SW(c0 + j)];
        sb[c0 + j] = (int)run;
        hcur[SW(c0 + j)] = run;                   // becomes the cursor
        run += cnt;
    }
    if (t == BB - 1) sb[NC] = (int)run;
    __syncthreads();

    // ---- scatter (positions via LDS cursor; p2 loaded vectorized) ----
    const float* P2 = p2 + (size_t)b * NPTS * 3;
    float4 r2[6];
    {
        const float4* P24 = (const float4*)P2;
#pragma unroll
        for (int j = 0; j < 6; ++j) r2[j] = P24[t * 6 + j];
    }
    const float* rf2 = (const float*)r2;
    const int base = b * NPTS;
#pragma unroll
    for (int j = 0; j < PPT; ++j) {
        const unsigned int pos = atomicAdd(&hcur[SW(pc[j])], 1u);
        const int gp = base + (int)pos;
        wsorted[gp] = make_float4(px[j], py[j], pz[j], pw[j]);
        p2s[gp] = make_float4(rf2[3 * j], rf2[3 * j + 1], rf2[3 * j + 2], 0.0f);
    }
}

// ---------------- phase 1 (verified round-14 version) ----------------
template<int S>
__device__ __forceinline__ void scan_batched(const float4* __restrict__ W,
                                             const int* __restrict__ st,
                                             int cx, int cy, int cz,
                                             float m2x, float m2y, float m2z,
                                             float q2, int qpos, int sl,
                                             int l[KNN])
{
    constexpr int Wd = 2 * S + 1;
    constexpr int R  = Wd * Wd;
    constexpr int CH = 5;               // prime-chunk width
    const int IMAX = 0x7FFFFFFF;
    int J0[R], J1[R];
#pragma unroll
    for (int r = 0; r < R; ++r) {
        const int dy = r % Wd - S, dz = r / Wd - S;   // compile-time
        const int ay = cy + dy, az = cz + dz;
        const bool ok = ((unsigned)ay < G) && ((unsigned)az < G);
        const int cbase = (az << 10) | (ay << 5);
        const int lo = cbase + max(cx - S, 0);
        const int hi = cbase + min(cx + S, G - 1) + 1;
        J0[r] = ok ? st[lo] : 0;                      // group-broadcast loads
        J1[r] = ok ? st[hi] : 0;
    }
#pragma unroll
    for (int base = 0; base < R; base += CH) {
        float4 P[CH];
#pragma unroll
        for (int c = 0; c < CH; ++c) {
            const int r = base + c;                   // compile-time
            if (r < R) {
                const int j = min(J0[r] + sl, NPTS - 1);  // clamped, harmless
                P[c] = W[j];                          // 16 consecutive float4
            }
        }
#pragma unroll
        for (int c = 0; c < CH; ++c) {
            const int r = base + c;
            if (r < R) {
                const int j1 = J1[r];
                int j = J0[r] + sl;
                if (j < j1) {
                    float4 c4 = P[c];                 // primed, in flight
                    while (true) {
                        const int jn = j + WPB;
                        const bool more = jn < j1;
                        float4 nx;
                        if (more) nx = W[jn];         // prefetch next (contig)
                        const float d2 = fmaf(m2x, c4.x,
                                         fmaf(m2y, c4.y,
                                         fmaf(m2z, c4.z, c4.w + q2)));
                        int key = (__float_as_int(d2) & MASK13) | j;
                        key = (j == qpos) ? IMAX : key;
                        ins1(l, key);
                        if (!more) break;
                        c4 = nx; j = jn;
                    }
                }
            }
        }
    }
}

__global__ __launch_bounds__(P1BLOCK)
void phase1(const float4* __restrict__ wsorted, const float4* __restrict__ p2s,
            const int* __restrict__ starts, float* __restrict__ out,
            int* __restrict__ nfail, int* __restrict__ worklist)
{
    __shared__ int mv[P1Q * MVSTR];          // 32*161*4 = 20.6 KB

    // batch in bit0: pair (2g, 2g+1) = same spatial group, different batch.
    const int bid   = blockIdx.x;
    const int batch = bid & 1;
    const int g     = bid >> 1;              // 0..255 spatial group
    const int tid   = threadIdx.x;
    // TRANSPOSED map: a 16-lane group owns all 16 slices of one query.
    const int qi    = tid >> 4;              // 0..31 query within block
    const int sl    = tid & 15;              // 0..15 slice
    const int qpos  = (g << 5) + qi;

    const float4* W  = wsorted + batch * NPTS;
    const float4* P2 = p2s + batch * NPTS;
    const int*    st = starts + batch * (NC + 1);

    const float4 qp = W[qpos];
    const int cx = min(max((int)floorf((qp.x - BMIN) * INVH), 0), G - 1);
    const int cy = min(max((int)floorf((qp.y - BMIN) * INVH), 0), G - 1);
    const int cz = min(max((int)floorf((qp.z - BMIN) * INVH), 0), G - 1);
    const float lox = BMIN + cx * H, loy = BMIN + cy * H, loz = BMIN + cz * H;
    const float df = fminf(fminf(fminf(qp.x - lox, lox + H - qp.x),
                                 fminf(qp.y - loy, loy + H - qp.y)),
                           fminf(qp.z - loz, loz + H - qp.z));
    const float m2x = -2.0f * qp.x, m2y = -2.0f * qp.y, m2z = -2.0f * qp.z;
    const float q2 = qp.w;
    const int IMAX = 0x7FFFFFFF;

    // per-query reach (uniform across the 16-lane group)
    const int sCov = (q2 > 4.8f) ? 2 : 1;

    int l[KNN];
#pragma unroll
    for (int k = 0; k < KNN; ++k) l[k] = IMAX;

    if (sCov == 1)
        scan_batched<1>(W, st, cx, cy, cz, m2x, m2y, m2z, q2, qpos, sl, l);
    else
        scan_batched<2>(W, st, cx, cy, cz, m2x, m2y, m2z, q2, qpos, sl, l);

#pragma unroll
    for (int k = 0; k < KNN; ++k) mv[qi * MVSTR + sl * KNN + k] = l[k];
    __syncthreads();

    float v = 0.0f;
    if (tid < P1Q) {
        int M[KNN];
#pragma unroll
        for (int k = 0; k < KNN; ++k) M[k] = IMAX;
#pragma unroll
        for (int e = 0; e < WPB; ++e) {
            int p[KNN];
#pragma unroll
            for (int k = 0; k < KNN; ++k) p[k] = mv[tid * MVSTR + e * KNN + k];
            merge_sorted(M, p);
        }

        const float tau = __int_as_float(M[KNN - 1] & MASK13);
        // recompute this query's sCov (tid-th query of the block)
        const float4 qq = W[(g << 5) + tid];
        const int sc = (qq.w > 4.8f) ? 2 : 1;
        const int qcx = min(max((int)floorf((qq.x - BMIN) * INVH), 0), G - 1);
        const int qcy = min(max((int)floorf((qq.y - BMIN) * INVH), 0), G - 1);
        const int qcz = min(max((int)floorf((qq.z - BMIN) * INVH), 0), G - 1);
        const float qlx = BMIN + qcx * H, qly = BMIN + qcy * H, qlz = BMIN + qcz * H;
        const float qdf = fminf(fminf(fminf(qq.x - qlx, qlx + H - qq.x),
                                      fminf(qq.y - qly, qly + H - qq.y)),
                                fminf(qq.z - qlz, qlz + H - qq.z));
        const float R = (float)sc * H + qdf;          // coverage radius
        const bool covered = (tau <= R * R * 0.996f); // truncation margin
        if (covered) {
            float s1x = 0, s1y = 0, s1z = 0, s2x = 0, s2y = 0, s2z = 0;
#pragma unroll
            for (int k = 0; k < KNN; ++k) {
                const int j = M[k] & (NPTS - 1);
                const float4 c4 = W[j];
                const float4 n2 = P2[j];
                s1x += c4.x; s1y += c4.y; s1z += c4.z;
                s2x += n2.x; s2y += n2.y; s2z += n2.z;
            }
            const float4 p2v = P2[(g << 5) + tid];
            const float dx = (s1x * 0.1f - qq.x) - (s2x * 0.1f - p2v.x);
            const float dy2 = (s1y * 0.1f - qq.y) - (s2y * 0.1f - p2v.y);
            const float dz2 = (s1z * 0.1f - qq.z) - (s2z * 0.1f - p2v.z);
            v = fabsf(dx) + fabsf(dy2) + fabsf(dz2);
        } else {
            const int wi = atomicAdd(nfail, 1);
            worklist[wi] = (batch << 16) | ((g << 5) + tid);
        }
    }
    if (tid < 64) {   // whole first wave -> shuffles well-defined
#pragma unroll
        for (int off = 32; off >= 1; off >>= 1) v += __shfl_down(v, off);
        if (tid == 0)
            atomicAdd(out, v * (1.0f / (float)(NB * NPTS * 3)));
    }
}

// ---------------- phase 2: wave-per-query exact brute force ----------------
constexpr int P2BLK = 256;
constexpr int P2GRID = 512;

__global__ __launch_bounds__(P2BLK)
void phase2(const float4* __restrict__ wsorted, const float4* __restrict__ p2s,
            const int* __restrict__ nfail, const int* __restrict__ worklist,
            float* __restrict__ out)
{
    const int lane = threadIdx.x & 63;
    const int wv   = threadIdx.x >> 6;
    const int wid  = blockIdx.x * (P2BLK / 64) + wv;
    const int NW   = P2GRID * (P2BLK / 64);
    const int nf   = *nfail;
    const int IMAX = 0x7FFFFFFF;
    float acc = 0.0f;

    for (int i = wid; i < nf; i += NW) {
        const int e = worklist[i];
        const int batch = e >> 16, qpos = e & 0xFFFF;
        const float4* W  = wsorted + batch * NPTS;
        const float4* P2 = p2s + batch * NPTS;
        const float4 qp = W[qpos];
        const float m2x = -2.0f * qp.x, m2y = -2.0f * qp.y, m2z = -2.0f * qp.z;
        const float q2 = qp.w;

        int l[KNN];
#pragma unroll
        for (int k = 0; k < KNN; ++k) l[k] = IMAX;

#pragma unroll 2
        for (int it = 0; it < NPTS / 128; ++it) {
            const int ja = it * 128 + lane, jb = ja + 64;
            const float4 ca = W[ja];
            const float4 cb = W[jb];
            const float da = fmaf(m2x, ca.x, fmaf(m2y, ca.y, fmaf(m2z, ca.z, ca.w + q2)));
            const float db = fmaf(m2x, cb.x, fmaf(m2y, cb.y, fmaf(m2z, cb.z, cb.w + q2)));
            int ka = (__float_as_int(da) & MASK13) | ja;
            int kb = (__float_as_int(db) & MASK13) | jb;
            ka = (ja == qpos) ? IMAX : ka;
            kb = (jb == qpos) ? IMAX : kb;
            ins2(l, ka, kb);
        }
        for (int off = 1; off < 64; off <<= 1) {
            int p[KNN];
#pragma unroll
            for (int k = 0; k < KNN; ++k) p[k] = __shfl_xor(l[k], off);
            merge_sorted(l, p);
        }
        float s1x = 0, s1y = 0, s1z = 0, s2x = 0, s2y = 0, s2z = 0;
#pragma unroll
        for (int k = 0; k < KNN; ++k) {
            const int j = l[k] & (NPTS - 1);
            const float4 c4 = W[j];
            const float4 n2 = P2[j];
            s1x += c4.x; s1y += c4.y; s1z += c4.z;
            s2x += n2.x; s2y += n2.y; s2z += n2.z;
        }
        const float4 p2v = P2[qpos];
        const float dx = (s1x * 0.1f - qp.x) - (s2x * 0.1f - p2v.x);
        const float dy = (s1y * 0.1f - qp.y) - (s2y * 0.1f - p2v.y);
        const float dz = (s1z * 0.1f - qp.z) - (s2z * 0.1f - p2v.z);
        if (lane == 0) acc += fabsf(dx) + fabsf(dy) + fabsf(dz);
    }

    if (lane == 0 && acc != 0.0f)
        atomicAdd(out, acc * (1.0f / (float)(NB * NPTS * 3)));
}

// ---------------- tiny-workspace fallback (O(N^2), verified) ----------------
constexpr int FB_WPB = 8;
constexpr int FB_BLOCK = QPB * FB_WPB;  // 512
constexpr int CHUNK = NPTS / FB_WPB;

__global__ void prep_pack(const float* __restrict__ p, float4* __restrict__ w) {
    const int i = blockIdx.x * blockDim.x + threadIdx.x;
    if (i < NB * NPTS) {
        const float x = p[3 * i], y = p[3 * i + 1], z = p[3 * i + 2];
        w[i] = make_float4(x, y, z, fmaf(x, x, fmaf(y, y, z * z)));
    }
}

__global__ __launch_bounds__(FB_BLOCK, 2)
void knn_lap(const float4* __restrict__ w1, const float* __restrict__ p2,
             float* __restrict__ out)
{
    __shared__ int mv[FB_WPB * KNN * QPB];
    const int batch = blockIdx.x >> 7;
    const int qbase = (blockIdx.x & 127) << 6;
    const int lane  = threadIdx.x & 63;
    const int wv    = __builtin_amdgcn_readfirstlane(threadIdx.x >> 6);
    const int query = qbase + lane;
    const float4* Wb = w1 + batch * NPTS;
    const float4 qp = Wb[query];
    const float m2x = -2.0f * qp.x, m2y = -2.0f * qp.y, m2z = -2.0f * qp.z;
    const float q2 = qp.w;
    const int IMAX = 0x7FFFFFFF;
    int l[KNN];
#pragma unroll
    for (int k = 0; k < KNN; ++k) l[k] = IMAX;
    const int c0 = wv * CHUNK;
    const float4* cand = Wb + c0;
#pragma unroll 4
    for (int i = 0; i < CHUNK; i += 2) {
        const float4 ca = cand[i];
        const float4 cb = cand[i + 1];
        const int ja = c0 + i, jb = ja + 1;
        const float da = fmaf(m2x, ca.x, fmaf(m2y, ca.y, fmaf(m2z, ca.z, ca.w + q2)));
        const float db = fmaf(m2x, cb.x, fmaf(m2y, cb.y, fmaf(m2z, cb.z, cb.w + q2)));
        int ka = (__float_as_int(da) & MASK13) | ja;
        int kb = (__float_as_int(db) & MASK13) | jb;
        ka = (ja == query) ? IMAX : ka;
        kb = (jb == query) ? IMAX : kb;
        ins2(l, ka, kb);
    }
#pragma unroll
    for (int k = 0; k < KNN; ++k) mv[(wv * KNN + k) * QPB + lane] = l[k];
    __syncthreads();
    if (threadIdx.x < QPB) {
        int m[KNN];
#pragma unroll
        for (int k = 0; k < KNN; ++k) m[k] = IMAX;
#pragma unroll
        for (int e = 0; e < FB_WPB; ++e) {
            int p[KNN];
#pragma unroll
            for (int k = 0; k < KNN; ++k) p[k] = mv[(e * KNN + k) * QPB + lane];
            merge_sorted(m, p);
        }
        const float* P2b = p2 + (size_t)batch * NPTS * 3;
        float s1x = 0, s1y = 0, s1z = 0, s2x = 0, s2y = 0, s2z = 0;
#pragma unroll
        for (int k = 0; k < KNN; ++k) {
            const int j = m[k] & (NPTS - 1);
            const float4 c = Wb[j];
            s1x += c.x; s1y += c.y; s1z += c.z;
            s2x += P2b[3 * j + 0]; s2y += P2b[3 * j + 1]; s2z += P2b[3 * j + 2];
        }
        const int q = qbase + threadIdx.x;
        const float p2x = P2b[3 * q + 0], p2y = P2b[3 * q + 1], p2z = P2b[3 * q + 2];
        const float dx = (s1x * 0.1f - qp.x) - (s2x * 0.1f - p2x);
        const float dy = (s1y * 0.1f - qp.y) - (s2y * 0.1f - p2y);
        const float dz = (s1z * 0.1f - qp.z) - (s2z * 0.1f - p2z);
        float v = fabsf(dx) + fabsf(dy) + fabsf(dz);
#pragma unroll
        for (int off = 32; off >= 1; off >>= 1) v += __shfl_down(v, off);
        if (threadIdx.x == 0)
            atomicAdd(out, v * (1.0f / (float)(NB * NPTS * 3)));
    }
}

// ---------------- launcher ----------------
extern "C" void kernel_launch(void* const* d_in, const int* in_sizes, int n_in,
                              void* d_out, int out_size, void* d_ws, size_t ws_size,
                              hipStream_t stream) {
    const float* p1 = (const float*)d_in[0];
    const float* p2 = (const float*)d_in[1];
    float* out = (float*)d_out;

    size_t off = 0;
    float4* w       = (float4*)d_ws;               off += (size_t)NB * NPTS * 16;
    int*    hist    = (int*)((char*)d_ws + off);   off += (size_t)NB * NC * 4;
    int*    starts  = (int*)((char*)d_ws + off);   off += (size_t)NB * (NC + 1) * 4 + 8;
    int*    cellof  = (int*)((char*)d_ws + off);   off += (size_t)NB * NPTS * 4;
    float4* wsorted = (float4*)((char*)d_ws + off); off += (size_t)NB * NPTS * 16;
    float4* p2s     = (float4*)((char*)d_ws + off); off += (size_t)NB * NPTS * 16;
    int*    nfail   = (int*)((char*)d_ws + off);   off += 512;
    int*    worklist= (int*)((char*)d_ws + off);   off += (size_t)NB * NPTS * 4;
    (void)hist; (void)cellof;   // no longer used (build is LDS-local)

    if (ws_size < off) {  // tiny workspace: brute force
        hipMemsetAsync(out, 0, sizeof(float), stream);
        prep_pack<<<(NB * NPTS + 255) / 256, 256, 0, stream>>>(p1, w);
        knn_lap<<<NB * (NPTS / QPB), FB_BLOCK, 0, stream>>>(w, p2, out);
        return;
    }

    build_all<<<NB, BB, 0, stream>>>(p1, p2, starts, wsorted, p2s, out, nfail);
    phase1<<<NB * (NPTS / P1Q), P1BLOCK, 0, stream>>>(wsorted, p2s, starts, out,
                                                      nfail, worklist);
    phase2<<<P2GRID, P2BLK, 0, stream>>>(wsorted, p2s, nfail, worklist, out);
}